// Round 6
// baseline (6852.829 us; speedup 1.0000x reference)
//
#include <hip/hip_runtime.h>
#include <hip/hip_bf16.h>

// Problem constants
#define T_LEN 2048
#define E_DIM 300
#define H_DIM 512
#define G_DIM 2048   // 4*H
#define NBLK  32     // worker blocks per direction
#define UPB   16     // hidden units per block (H/NBLK)
#define RING  512    // h ring slots (= steps per phase)
#define PHASE 512    // steps per k_rnn launch
#define NPHASE 4

// Workspace layout (bytes), total 38,469,632 (<= proven-good 38.8 MB):
//   [0,        33554432)  gx   bf16 [4][2048 t][2048 g-sliced]
//   [33554432, 38469632)  x    f32  [2][2048][300]      (dead after k_gemm)
// overlapping x after k_gemm (k_init writes these):
//   [33554432, +4194304)  hring f32 [512 slot][2 d][2 s][512]
//   [37748736, +131072)   flags u32 [512 slot][2 d][32 bb]
//   [37879808, +8192)     csave f32 [2 d][2 s][512]
//   [37888000, +64)       claim u32 [16]
#define WS_GX    0
#define WS_X     33554432
#define WS_HR    33554432
#define WS_FLAG  37748736
#define WS_CS    37879808
#define WS_CLAIM 37888000

typedef float v2f __attribute__((ext_vector_type(2)));

__device__ __forceinline__ float sigmoid_fast(float x) {
    return 1.f / (1.f + __expf(-x));
}
__device__ __forceinline__ float tanh_fast(float x) {
    x = fminf(fmaxf(x, -15.f), 15.f);
    float e = __expf(-2.f * x);
    return (1.f - e) / (1.f + e);
}

// ---------------- k1: embedding gather ----------------
__global__ void k_gather(const int* __restrict__ sentA, const int* __restrict__ sentB,
                         const float* __restrict__ emb, float* __restrict__ x) {
    const int s = blockIdx.y;
    const int* sent = s ? sentB : sentA;
    const int t0 = blockIdx.x * 16;
    for (int idx = threadIdx.x; idx < 16 * 300; idx += 256) {
        int r = idx / 300, e = idx - r * 300;
        int t = t0 + r;
        int row = sent[t];
        x[((size_t)(s * 2048 + t)) * 300 + e] = emb[(size_t)row * 300 + e];
    }
}

// ---------------- k2: gx = x @ w_ih^T + (b_ih + b_hh), bf16, block-sliced layout ----------------
__global__ __launch_bounds__(256) void k_gemm(const float* __restrict__ x,
                                              const float* __restrict__ w_ih,
                                              const float* __restrict__ b_ih,
                                              const float* __restrict__ b_hh,
                                              __hip_bfloat16* __restrict__ gx) {
    __shared__ float xs[32 * 108];
    __shared__ float ws_[64 * 108];
    const int gi = blockIdx.x, ti = blockIdx.y, z = blockIdx.z;
    const int d = z >> 1, s = z & 1;
    const int t0 = ti * 32, g0 = gi * 64;
    const int tg = threadIdx.x & 15, tt = threadIdx.x >> 4;
    const float* wbase = w_ih + (size_t)d * G_DIM * E_DIM;

    float acc[2][4];
#pragma unroll
    for (int j = 0; j < 2; ++j)
#pragma unroll
        for (int i = 0; i < 4; ++i) acc[j][i] = 0.f;

    for (int e0 = 0; e0 < 300; e0 += 100) {
        for (int idx = threadIdx.x; idx < 32 * 25; idx += 256) {
            int r = idx / 25, c = idx - r * 25;
            float4 v = *(const float4*)(x + ((size_t)(s * 2048 + t0 + r)) * 300 + e0 + c * 4);
            *(float4*)&xs[r * 108 + c * 4] = v;
        }
        for (int idx = threadIdx.x; idx < 64 * 25; idx += 256) {
            int r = idx / 25, c = idx - r * 25;
            float4 v = *(const float4*)(wbase + (size_t)(g0 + r) * 300 + e0 + c * 4);
            *(float4*)&ws_[r * 108 + c * 4] = v;
        }
        __syncthreads();

        for (int c = 0; c < 25; ++c) {
            float4 xv[2], wv[4];
#pragma unroll
            for (int j = 0; j < 2; ++j) xv[j] = *(const float4*)&xs[(tt + 16 * j) * 108 + c * 4];
#pragma unroll
            for (int i = 0; i < 4; ++i) wv[i] = *(const float4*)&ws_[(tg + 16 * i) * 108 + c * 4];
#pragma unroll
            for (int j = 0; j < 2; ++j)
#pragma unroll
                for (int i = 0; i < 4; ++i)
                    acc[j][i] += xv[j].x * wv[i].x + xv[j].y * wv[i].y +
                                 xv[j].z * wv[i].z + xv[j].w * wv[i].w;
        }
        __syncthreads();
    }

#pragma unroll
    for (int i = 0; i < 4; ++i) {
        int g = g0 + tg + 16 * i;
        float bias = b_ih[d * G_DIM + g] + b_hh[d * G_DIM + g];
        int pos = ((g >> 4) & 31) * 64 + (g >> 9) * 16 + (g & 15);
#pragma unroll
        for (int j = 0; j < 2; ++j) {
            int t = t0 + tt + 16 * j;
            int tout = d ? (T_LEN - 1 - t) : t;
            float v = acc[j][i] + bias;
            gx[(((size_t)(d * 2 + s) * T_LEN + tout) << 11) + pos] = __float2bfloat16(v);
        }
    }
}

// ---------------- k_init: initialize hring slot0 / flags / csave / claim ----------------
// Runs AFTER k_gemm (these regions overlap the then-dead x buffer).
__global__ void k_init(unsigned int* __restrict__ flags, float* __restrict__ hr,
                       float* __restrict__ cs, unsigned int* __restrict__ claim) {
    int idx = blockIdx.x * 256 + threadIdx.x;
    if (idx < RING * 2 * 32) flags[idx] = (idx < 64) ? 1u : 0u;  // slot0 flags = 1 (h[0] ready)
    if (idx < 2048) hr[idx] = 0.f;    // h[0] = 0 (slot 0: [2 d][2 s][512])
    if (idx < 2048) cs[idx] = 0.f;    // c_0 = 0
    if (idx < 16) claim[idx] = 0u;
}

// ---------------- k3: recurrent LSTM phase (512 steps), XCD-pinned ----------------
// h ring: plain f32, every address first-touch per launch (L1 staleness impossible);
// producers: plain write-through stores -> vmcnt(0) -> barrier -> one flag atomic_swap.
// consumers: wave0 polls 32 per-block flags via atomic_or(0) sc0 (XCD-L2-executing).
__global__ __launch_bounds__(256, 1) void k_rnn(const float* __restrict__ w_hh,
                                                const __hip_bfloat16* __restrict__ gx,
                                                float* __restrict__ hr,
                                                unsigned int* __restrict__ flags,
                                                float* __restrict__ cs,
                                                unsigned int* __restrict__ claim,
                                                int t0, int phase) {
    unsigned int xcc;
    asm("s_getreg_b32 %0, hwreg(HW_REG_XCC_ID)" : "=s"(xcc));
    xcc &= 7u;
    if (xcc > 1u) return;

    __shared__ float hlds[2 * H_DIM];    // 4 KB
    __shared__ float pacc[128 * 68];     // 34 KB
    __shared__ float big_pad[12288];     // 48 KB occupancy limiter -> 1 block/CU
    __shared__ unsigned int slot_s;

    const int tid = threadIdx.x;
    ((volatile float*)big_pad)[tid] = 0.f;   // keep pad allocated

    if (tid == 0) slot_s = atomicAdd(&claim[phase * 2 + xcc], 1u);
    __syncthreads();
    if (slot_s >= NBLK) return;

    const int d = (int)xcc;
    const int bb = (int)slot_s;
    const int lane = tid & 63;
    const int w = tid >> 6;
    // reduce/gate identity: physical pacc row r = tid>>1 = (s*16+ul)*4 + q
    const int r_g  = tid >> 1;
    const int half = tid & 1;
    const int q_g  = r_g & 3;
    const int ul_g = (r_g >> 2) & 15;
    const int s_g  = r_g >> 6;

    // persistent weights, row-paired: wreg2[r2][kb] = { W[w*512+bb*16+2r2][k], W[+1][k] }
    v2f wreg2[8][8];
#pragma unroll
    for (int r2 = 0; r2 < 8; ++r2)
#pragma unroll
        for (int kb = 0; kb < 8; ++kb) {
            const float* wp = w_hh + ((size_t)d * G_DIM + w * 512 + bb * 16 + 2 * r2) * H_DIM
                            + kb * 64 + lane;
            v2f t2; t2.x = wp[0]; t2.y = wp[H_DIM];
            wreg2[r2][kb] = t2;
        }

    // carry c_state across phases (only meaningful for state threads)
    float c_state = cs[(d * 2 + s_g) * H_DIM + bb * UPB + ul_g];

    // gx prefetch pipeline (1 step ahead)
    const __hip_bfloat16* gxp = gx + (((size_t)(d * 2 + s_g) * T_LEN) << 11)
                              + bb * 64 + q_g * 16 + ul_g;
    float gx_cur = (float)gxp[(size_t)t0 << 11];

    int budget = 1 << 21;   // cumulative poll budget: anomaly -> bounded wrong exit, no hang

    for (int i = 0; i < PHASE; ++i) {
        const int t = t0 + i;

        // ---- detect: wave0 polls the 32 producer flags for slot i ----
        if (w == 0) {
            const unsigned int want = (unsigned int)(t + 1);
            unsigned int* fp = flags + ((size_t)i * 2 + d) * 32 + (lane & 31);
            for (;;) {
                unsigned int f = want;
                if (lane < 32) {
                    asm volatile(
                        "global_atomic_or %0, %1, %2, off sc0\n\t"
                        "s_waitcnt vmcnt(0)"
                        : "=v"(f) : "v"(fp), "v"(0u) : "memory");
                }
                if (__all(f == want)) break;
                if (--budget < 0) break;
            }
        }
        __syncthreads();   // B0: release all waves to load h

        // ---- load h slot i (plain loads; first touch this launch -> L2-fresh) ----
        const float* hbase = hr + ((size_t)i * 2 + d) * 1024;   // [2 s][512]
        const int o = w * 128 + lane;
        float a0 = hbase[o], a1 = hbase[o + 64], a2 = hbase[512 + o], a3 = hbase[512 + o + 64];
        hlds[o] = a0; hlds[o + 64] = a1; hlds[512 + o] = a2; hlds[512 + o + 64] = a3;
        __syncthreads();   // B1: full h visible to all waves

        // prefetch next step's gate input (completes during compute)
        float gx_nxt = (i + 1 < PHASE) ? (float)gxp[(size_t)(t + 1) << 11] : 0.f;

        // full h fragment for this lane
        float hv[2][8];
#pragma unroll
        for (int s = 0; s < 2; ++s)
#pragma unroll
            for (int kb = 0; kb < 8; ++kb)
                hv[s][kb] = hlds[s * H_DIM + kb * 64 + lane];

        // matvec partials: 8 row-pairs x 2 sentences per lane, packed fp32 FMA
        v2f acc2[8][2];
#pragma unroll
        for (int r2 = 0; r2 < 8; ++r2) {
            acc2[r2][0] = (v2f)(0.f);
            acc2[r2][1] = (v2f)(0.f);
        }
#pragma unroll
        for (int kb = 0; kb < 8; ++kb) {
#pragma unroll
            for (int s = 0; s < 2; ++s) {
                float h0 = hv[s][kb];
                v2f h2; h2.x = h0; h2.y = h0;
#pragma unroll
                for (int r2 = 0; r2 < 8; ++r2)
                    acc2[r2][s] += wreg2[r2][kb] * h2;
            }
        }

        // publish partials; pacc row = (s*16 + unit)*4 + gate(w) -> conflict-free reduce
#pragma unroll
        for (int r2 = 0; r2 < 8; ++r2)
#pragma unroll
            for (int s = 0; s < 2; ++s) {
                pacc[((s * 16 + 2 * r2 + 0) * 4 + w) * 68 + lane] = acc2[r2][s].x;
                pacc[((s * 16 + 2 * r2 + 1) * 4 + w) * 68 + lane] = acc2[r2][s].y;
            }
        __syncthreads();   // B2

        // reduce physical row r_g = tid>>1 (2 threads x 32 values)
        const float4* pr = (const float4*)&pacc[r_g * 68 + half * 32];
        float4 sv = pr[0];
#pragma unroll
        for (int j2 = 1; j2 < 8; ++j2) {
            float4 q4 = pr[j2];
            sv.x += q4.x; sv.y += q4.y; sv.z += q4.z; sv.w += q4.w;
        }
        float v = (sv.x + sv.y) + (sv.z + sv.w);
        v += __shfl_xor(v, 1, 64);
        v += gx_cur;
        float act = (q_g == 2) ? tanh_fast(v) : sigmoid_fast(v);

        // gather i/f/g/o within the 8-lane group (gates of one unit are adjacent)
        const int g0l = lane & ~7;
        float si  = __shfl(act, g0l + 0, 64);
        float sf  = __shfl(act, g0l + 2, 64);
        float tgg = __shfl(act, g0l + 4, 64);
        float so  = __shfl(act, g0l + 6, 64);
        if ((lane & 7) == 0) {
            c_state = sf * c_state + si * tgg;
            float h_new = so * tanh_fast(c_state);
            // plain write-through store into ring slot (i+1)&511
            hr[((size_t)((i + 1) & (RING - 1)) * 2 + d) * 1024 + s_g * 512 + bb * UPB + ul_g] = h_new;
            if (i == PHASE - 1)
                cs[(d * 2 + s_g) * H_DIM + bb * UPB + ul_g] = c_state;
        }
        gx_cur = gx_nxt;

        // drain this wave's stores to L2, join block, then post the block flag
        asm volatile("s_waitcnt vmcnt(0)" ::: "memory");
        __syncthreads();   // B3
        if (tid == 0) {
            unsigned int* fdst = flags + ((size_t)((i + 1) & (RING - 1)) * 2 + d) * 32 + bb;
            unsigned int fv = (unsigned int)(t + 2);
            asm volatile("global_atomic_swap %0, %1, off" :: "v"(fdst), "v"(fv) : "memory");
        }
    }
}

// ---------------- k4: head ----------------
__global__ __launch_bounds__(512) void k_head(const float* __restrict__ hr,
                                              const float* __restrict__ bi_w,
                                              const float* __restrict__ bi_b,
                                              const float* __restrict__ blA,
                                              const float* __restrict__ blB,
                                              const float* __restrict__ bl_b,
                                              const float* __restrict__ out_w,
                                              const float* __restrict__ out_b,
                                              float* __restrict__ out) {
    __shared__ float enc[2][512];
    __shared__ float red[8];
    const int tid = threadIdx.x;
    const float bw0 = bi_w[0], bw1 = bi_w[1], bib = bi_b[0];
    {
        int u = tid;
        // h[2048] lives in ring slot 2048 & 511 = 0
        float hfA = hr[(0 * 2 + 0) * 1024 + 0 * 512 + u];
        float hbA = hr[(0 * 2 + 1) * 1024 + 0 * 512 + u];
        float hfB = hr[(0 * 2 + 0) * 1024 + 1 * 512 + u];
        float hbB = hr[(0 * 2 + 1) * 1024 + 1 * 512 + u];
        enc[0][u] = bw0 * hfA + bw1 * hbA + bib;
        enc[1][u] = bw0 * hfB + bw1 * hbB + bib;
    }
    __syncthreads();
    const int j = tid;
    float acc = bl_b[j];
#pragma unroll 4
    for (int u = 0; u < 512; ++u)
        acc += enc[0][u] * blA[u * 512 + j] + enc[1][u] * blB[u * 512 + j];
    float contrib = tanh_fast(acc) * out_w[j];
#pragma unroll
    for (int m = 1; m < 64; m <<= 1) contrib += __shfl_xor(contrib, m, 64);
    if ((tid & 63) == 0) red[tid >> 6] = contrib;
    __syncthreads();
    if (tid == 0) {
        float s = 0.f;
#pragma unroll
        for (int i = 0; i < 8; ++i) s += red[i];
        s += out_b[0];
        out[0] = sigmoid_fast(s);
    }
}

extern "C" void kernel_launch(void* const* d_in, const int* in_sizes, int n_in,
                              void* d_out, int out_size, void* d_ws, size_t ws_size,
                              hipStream_t stream) {
    const int*   sentA = (const int*)d_in[0];
    const int*   sentB = (const int*)d_in[1];
    // d_in[2] = hidden (unused by forward)
    const float* emb   = (const float*)d_in[3];
    const float* w_ih  = (const float*)d_in[4];
    const float* w_hh  = (const float*)d_in[5];
    const float* b_ih  = (const float*)d_in[6];
    const float* b_hh  = (const float*)d_in[7];
    const float* bi_w  = (const float*)d_in[8];
    const float* bi_b  = (const float*)d_in[9];
    const float* blA   = (const float*)d_in[10];
    const float* blB   = (const float*)d_in[11];
    const float* bl_b  = (const float*)d_in[12];
    const float* out_w = (const float*)d_in[13];
    const float* out_b = (const float*)d_in[14];
    float* out = (float*)d_out;

    char* ws = (char*)d_ws;
    __hip_bfloat16* gx    = (__hip_bfloat16*)(ws + WS_GX);
    float*          x     = (float*)(ws + WS_X);
    float*          hrng  = (float*)(ws + WS_HR);
    unsigned int*   flags = (unsigned int*)(ws + WS_FLAG);
    float*          csave = (float*)(ws + WS_CS);
    unsigned int*   claim = (unsigned int*)(ws + WS_CLAIM);

    k_gather<<<dim3(128, 2), 256, 0, stream>>>(sentA, sentB, emb, x);
    k_gemm<<<dim3(32, 64, 4), 256, 0, stream>>>(x, w_ih, b_ih, b_hh, gx);
    k_init<<<dim3(128), 256, 0, stream>>>(flags, hrng, csave, claim);
    for (int p = 0; p < NPHASE; ++p) {
        k_rnn<<<dim3(1024), 256, 0, stream>>>(w_hh, gx, hrng, flags, csave, claim,
                                              p * PHASE, p);
    }
    k_head<<<dim3(1), 512, 0, stream>>>(hrng, bi_w, bi_b, blA, blB, bl_b, out_w, out_b, out);
}